// Round 4
// baseline (7240.423 us; speedup 1.0000x reference)
//
#include <hip/hip_runtime.h>

// RecurrentNEFLayer on MI355X — persistent-kernel scan.
// 128 blocks = 8 batch-groups (32 rows) x 16 neuron-groups (128 neurons).
// Weights LDS-resident (bf16) for all 512 steps.
// r4: data atomics ELIMINATED. Per step: plain-store f32 partials -> barrier A
// -> 16-way slice-reduce (2 rows/block) -> bf16 s store -> barrier B (polled
// lazily next step). No zeroing pass, single partial/state buffers.

constexpr int CB   = 256;   // batch
constexpr int CT   = 512;   // time steps
constexpr int DIN  = 128;
constexpr int DST  = 128;
constexpr int DOUT = 64;
constexpr int DAUG = 256;   // DIN + DST

constexpr int NBG = 8;      // batch groups
constexpr int NNG = 16;     // neuron groups (blocks per barrier group)
constexpr int BT  = 32;     // batch rows per group
constexpr int NT  = 128;    // neurons per block

constexpr int EPAD = 264;   // 256 + 8 bf16 pad (row stride ≡ 4 dwords mod 32 → 2-way, free)
constexpr int APAD = 136;   // 128 + 8 bf16 pad

using f32x4  = __attribute__((ext_vector_type(4))) float;
using bf16x8 = __attribute__((ext_vector_type(8))) short;   // 8 bf16 in 4 VGPRs

__device__ __forceinline__ short f2b(float x) {   // f32 -> bf16 RNE
  unsigned u = __builtin_bit_cast(unsigned, x);
  u += 0x7fffu + ((u >> 16) & 1u);
  return (short)(u >> 16);
}
__device__ __forceinline__ short4 f2b4(float4 v) {
  return make_short4(f2b(v.x), f2b(v.y), f2b(v.z), f2b(v.w));
}

__global__ void nef_init(unsigned int* SfinZ, unsigned int* ctrs, float* out) {
  int idx = blockIdx.x * blockDim.x + threadIdx.x;
  int stride = gridDim.x * blockDim.x;
  for (int i = idx; i < CB * DST / 2; i += stride) SfinZ[i] = 0u;  // bf16 s=0
  for (int i = idx; i < CB * DOUT; i += stride) out[i] = 0.f;
  if (idx < 16 * 64) ctrs[idx] = 0u;                               // barrier ctrs
}

__global__ void __launch_bounds__(256) nef_main(
    const float* __restrict__ seq,  const float* __restrict__ enc,
    const float* __restrict__ gainp,const float* __restrict__ biasp,
    const float* __restrict__ sdec, const float* __restrict__ dec,
    float* __restrict__ out, float* __restrict__ Pbuf,
    unsigned short* __restrict__ Sfin, unsigned int* ctrs)
{
  __shared__ short E_lds[NT][EPAD];     // encoders tile  [n][k_aug]   67.6 KB
  __shared__ short SDT_lds[DST][APAD];  // state_dec^T    [d][n]       34.8 KB
  __shared__ short X_lds[BT][EPAD];     // [u_t | s_t]    [b][k_aug]   16.9 KB
  __shared__ short A_lds[BT][APAD];     // activations    [b][n]        8.7 KB
  __shared__ float gain_lds[NT];
  __shared__ float bias_lds[NT];

  const int tid  = threadIdx.x;
  const int bg   = blockIdx.x & 7;    // group's 16 blocks share an XCD (perf heuristic only)
  const int ng   = blockIdx.x >> 3;
  const int b0   = bg * BT;
  const int n0   = ng * NT;
  const int wave = tid >> 6;
  const int lane = tid & 63;
  const int l15  = lane & 15;
  const int lhi  = lane >> 4;         // 0..3
  const int kbase = lhi * 8;

  // ---- one-time: stage weights into LDS (bf16) ----
  for (int i = 0; i < 32; ++i) {                       // encoders: 128x256 f32
    int fidx = i * 256 + tid;
    int row = fidx >> 6, c4 = fidx & 63;
    const float4 v = *(const float4*)(enc + (size_t)(n0 + row) * DAUG + (c4 << 2));
    *(short4*)&E_lds[row][c4 << 2] = f2b4(v);
  }
  for (int i = 0; i < 16; ++i) {                       // state_decoders: transpose
    int fidx = i * 256 + tid;
    int n = fidx >> 5, c4 = fidx & 31;
    const float4 v = *(const float4*)(sdec + (size_t)(n0 + n) * DST + (c4 << 2));
    SDT_lds[(c4 << 2) + 0][n] = f2b(v.x);
    SDT_lds[(c4 << 2) + 1][n] = f2b(v.y);
    SDT_lds[(c4 << 2) + 2][n] = f2b(v.z);
    SDT_lds[(c4 << 2) + 3][n] = f2b(v.w);
  }
  if (tid < NT) { gain_lds[tid] = gainp[n0 + tid]; bias_lds[tid] = biasp[n0 + tid]; }

  unsigned int* ctr = ctrs + bg * 64;                 // one 256B-strided ctr per group
  float* Pgrp = Pbuf + (size_t)bg * NNG * BT * DST;   // group's 16 partial slots
  float* Pme  = Pgrp + (size_t)ng * BT * DST;         // this block's slot (16 KB)
  const int nsub0 = wave * 32, nsub1 = nsub0 + 16;

  // seq prefetch: 4 float4 per thread per step (32 rows x 32 float4-cols)
  float4 pu[4];
#pragma unroll
  for (int i = 0; i < 4; ++i) {
    int fidx = i * 256 + tid;
    int row = fidx >> 5, c4 = fidx & 31;
    pu[i] = *(const float4*)(seq + ((size_t)(b0 + row) * CT + 0) * DIN + (c4 << 2));
  }

  for (int t = 0; t < CT; ++t) {
    // ---- stage u-half (register prefetch -> LDS bf16); independent of s ----
#pragma unroll
    for (int i = 0; i < 4; ++i) {
      int fidx = i * 256 + tid;
      int row = fidx >> 5, c4 = fidx & 31;
      *(short4*)&X_lds[row][c4 << 2] = f2b4(pu[i]);
    }
    if (t + 1 < CT) {   // prefetch u_{t+1}; in flight across the poll below
#pragma unroll
      for (int i = 0; i < 4; ++i) {
        int fidx = i * 256 + tid;
        int row = fidx >> 5, c4 = fidx & 31;
        pu[i] = *(const float4*)(seq + ((size_t)(b0 + row) * CT + (t + 1)) * DIN + (c4 << 2));
      }
    }
    // ---- wait for s_t (barrier B of step t-1), then acquire ----
    if (t > 0) {
      if (tid == 0) {
        unsigned int tgt = 16u * (unsigned)(2 * t), guard = 0;
        while (__hip_atomic_load(ctr, __ATOMIC_RELAXED, __HIP_MEMORY_SCOPE_AGENT) < tgt) {
          __builtin_amdgcn_s_sleep(1);
          if (++guard > 200000u) break;
        }
        __threadfence();   // acquire: invalidate before reading Sfin
      }
      __syncthreads();
    }
    // ---- stage s-half: Sfin (bf16) -> LDS ----
#pragma unroll
    for (int i = 0; i < 4; ++i) {
      int fidx = i * 256 + tid;
      int row = fidx >> 5, c4 = fidx & 31;
      *(short4*)&X_lds[row][DIN + (c4 << 2)] =
          *(const short4*)&Sfin[(size_t)(b0 + row) * DST + (c4 << 2)];
    }
    __syncthreads();   // also covers one-time weight staging at t=0

    // ---- GEMM A: (32 x 256) @ (256 x 128) -> a; wave: 2 m-tiles x 2 n-tiles ----
    f32x4 acc00 = {0,0,0,0}, acc01 = {0,0,0,0}, acc10 = {0,0,0,0}, acc11 = {0,0,0,0};
#pragma unroll
    for (int kk = 0; kk < 8; ++kk) {
      bf16x8 a0 = *(const bf16x8*)&X_lds[l15][kk * 32 + kbase];
      bf16x8 a1 = *(const bf16x8*)&X_lds[16 + l15][kk * 32 + kbase];
      bf16x8 e0 = *(const bf16x8*)&E_lds[nsub0 + l15][kk * 32 + kbase];
      bf16x8 e1 = *(const bf16x8*)&E_lds[nsub1 + l15][kk * 32 + kbase];
      acc00 = __builtin_amdgcn_mfma_f32_16x16x32_bf16(a0, e0, acc00, 0, 0, 0);
      acc01 = __builtin_amdgcn_mfma_f32_16x16x32_bf16(a0, e1, acc01, 0, 0, 0);
      acc10 = __builtin_amdgcn_mfma_f32_16x16x32_bf16(a1, e0, acc10, 0, 0, 0);
      acc11 = __builtin_amdgcn_mfma_f32_16x16x32_bf16(a1, e1, acc11, 0, 0, 0);
    }
    {   // epilogue: relu(gain*x + bias) -> bf16 a-tile in LDS
      const int nc0 = nsub0 + l15, nc1 = nsub1 + l15;
      const float g0 = gain_lds[nc0], bi0 = bias_lds[nc0];
      const float g1 = gain_lds[nc1], bi1 = bias_lds[nc1];
#pragma unroll
      for (int j = 0; j < 4; ++j) {   // C/D: col=lane&15, row=(lane>>4)*4+j
        A_lds[lhi * 4 + j][nc0]      = f2b(fmaxf(g0 * acc00[j] + bi0, 0.f));
        A_lds[lhi * 4 + j][nc1]      = f2b(fmaxf(g1 * acc01[j] + bi1, 0.f));
        A_lds[16 + lhi * 4 + j][nc0] = f2b(fmaxf(g0 * acc10[j] + bi0, 0.f));
        A_lds[16 + lhi * 4 + j][nc1] = f2b(fmaxf(g1 * acc11[j] + bi1, 0.f));
      }
    }
    __syncthreads();

    if (t != CT - 1) {
      // ---- GEMM B: (32 x 128) @ (128 x 128) -> this block's f32 partial ----
      f32x4 p00 = {0,0,0,0}, p01 = {0,0,0,0}, p10 = {0,0,0,0}, p11 = {0,0,0,0};
      const int d0 = nsub0 + l15, d1 = nsub1 + l15;
#pragma unroll
      for (int kk = 0; kk < 4; ++kk) {
        bf16x8 a0 = *(const bf16x8*)&A_lds[l15][kk * 32 + kbase];
        bf16x8 a1 = *(const bf16x8*)&A_lds[16 + l15][kk * 32 + kbase];
        bf16x8 s0 = *(const bf16x8*)&SDT_lds[d0][kk * 32 + kbase];
        bf16x8 s1 = *(const bf16x8*)&SDT_lds[d1][kk * 32 + kbase];
        p00 = __builtin_amdgcn_mfma_f32_16x16x32_bf16(a0, s0, p00, 0, 0, 0);
        p01 = __builtin_amdgcn_mfma_f32_16x16x32_bf16(a0, s1, p01, 0, 0, 0);
        p10 = __builtin_amdgcn_mfma_f32_16x16x32_bf16(a1, s0, p10, 0, 0, 0);
        p11 = __builtin_amdgcn_mfma_f32_16x16x32_bf16(a1, s1, p11, 0, 0, 0);
      }
      // plain coalesced stores of the partial (no RMW, no contention)
#pragma unroll
      for (int j = 0; j < 4; ++j) {
        Pme[(size_t)(lhi * 4 + j) * DST + d0]        = p00[j];
        Pme[(size_t)(lhi * 4 + j) * DST + d1]        = p01[j];
        Pme[(size_t)(16 + lhi * 4 + j) * DST + d0]   = p10[j];
        Pme[(size_t)(16 + lhi * 4 + j) * DST + d1]   = p11[j];
      }
      // ---- barrier A: all 16 partials visible ----
      __syncthreads();   // drains each thread's stores to L2
      if (tid == 0) {
        __threadfence();                 // release: flush partials
        atomicAdd(ctr, 1u);
        unsigned int tgt = 16u * (unsigned)(2 * t + 1), guard = 0;
        while (__hip_atomic_load(ctr, __ATOMIC_RELAXED, __HIP_MEMORY_SCOPE_AGENT) < tgt) {
          __builtin_amdgcn_s_sleep(1);
          if (++guard > 200000u) break;
        }
        __threadfence();                 // acquire: invalidate before reading partials
      }
      __syncthreads();
      // ---- slice-reduce: this block reduces rows {2ng, 2ng+1} over 16 partials ----
      {
        const int r = 2 * ng + (tid >> 7);      // 0..31
        const int d = tid & 127;
        const float* bp = Pgrp + (size_t)r * DST + d;
        float s = 0.f;
#pragma unroll
        for (int p = 0; p < NNG; ++p) s += bp[(size_t)p * BT * DST];
        Sfin[(size_t)(b0 + r) * DST + d] = (unsigned short)f2b(s);
      }
      // ---- barrier B arrive (polled lazily at start of step t+1) ----
      __syncthreads();   // drains Sfin stores to L2
      if (tid == 0) {
        __threadfence();                 // release: flush Sfin
        atomicAdd(ctr, 1u);
      }
    } else {
      // ---- final step: out partial = a_final @ decoders[n0:n0+128] ----
      f32x4 o0 = {0,0,0,0}, o1 = {0,0,0,0};
      const int ocol = wave * 16 + l15;   // 4 waves x 16 = DOUT
#pragma unroll
      for (int kk = 0; kk < 4; ++kk) {
        bf16x8 a0 = *(const bf16x8*)&A_lds[l15][kk * 32 + kbase];
        bf16x8 a1 = *(const bf16x8*)&A_lds[16 + l15][kk * 32 + kbase];
        bf16x8 bfD;
#pragma unroll
        for (int j = 0; j < 8; ++j)
          bfD[j] = f2b(dec[(size_t)(n0 + kk * 32 + kbase + j) * DOUT + ocol]);
        o0 = __builtin_amdgcn_mfma_f32_16x16x32_bf16(a0, bfD, o0, 0, 0, 0);
        o1 = __builtin_amdgcn_mfma_f32_16x16x32_bf16(a1, bfD, o1, 0, 0, 0);
      }
#pragma unroll
      for (int j = 0; j < 4; ++j) {       // one-time 16-way K-split: atomics OK here
        atomicAdd(&out[(size_t)(b0 + lhi * 4 + j) * DOUT + ocol], o0[j]);
        atomicAdd(&out[(size_t)(b0 + 16 + lhi * 4 + j) * DOUT + ocol], o1[j]);
      }
    }
  }
}

extern "C" void kernel_launch(void* const* d_in, const int* in_sizes, int n_in,
                              void* d_out, int out_size, void* d_ws, size_t ws_size,
                              hipStream_t stream) {
  const float* seq   = (const float*)d_in[0];
  const float* enc   = (const float*)d_in[1];
  const float* gainp = (const float*)d_in[2];
  const float* biasp = (const float*)d_in[3];
  const float* sdec  = (const float*)d_in[4];
  const float* dec   = (const float*)d_in[5];
  float* out = (float*)d_out;

  // workspace: Pbuf f32 [8][16][32][128] = 2 MB | Sfin bf16 [256][128] = 64 KB | ctrs 4 KB
  float* Pbuf = (float*)d_ws;
  unsigned short* Sfin = (unsigned short*)((char*)d_ws + (size_t)NBG * NNG * BT * DST * 4);
  unsigned int* ctrs = (unsigned int*)((char*)Sfin + (size_t)CB * DST * 2);

  nef_init<<<128, 256, 0, stream>>>((unsigned int*)Sfin, ctrs, out);
  nef_main<<<dim3(NBG * NNG), dim3(256), 0, stream>>>(seq, enc, gainp, biasp,
                                                      sdec, dec, out, Pbuf, Sfin, ctrs);
}

// Round 6
// 1673.211 us; speedup vs baseline: 4.3273x; 4.3273x over previous
//
#include <hip/hip_runtime.h>

// RecurrentNEFLayer on MI355X — persistent-kernel scan.
// 128 blocks = 8 batch-groups (32 rows) x 16 neuron-groups (128 neurons).
// Weights LDS-resident (bf16) for all 512 steps.
// r5 (resubmitted r6 — prior round was an infra failure, kernel never ran):
// single barrier per step, ZERO cache-maintenance fences.
//  - s_{t+1} reduced via unsafeAtomicAdd (HW global_atomic_add_f32, memory-side LLC RMW)
//  - flag = integer atomicAdd; consumers poll with relaxed agent atomic loads
//  - S staged via relaxed agent atomic loads (bypass stale L1/L2)
//  - future S buffers zeroed via relaxed agent atomic stores (write-through)
// Memory-side coherence at the LLC makes this correct with no buffer_wbl2/inv.

constexpr int CB   = 256;   // batch
constexpr int CT   = 512;   // time steps
constexpr int DIN  = 128;
constexpr int DST  = 128;
constexpr int DOUT = 64;
constexpr int DAUG = 256;   // DIN + DST

constexpr int NBG = 8;      // batch groups
constexpr int NNG = 16;     // neuron groups (blocks per barrier group)
constexpr int BT  = 32;     // batch rows per group
constexpr int NT  = 128;    // neurons per block

constexpr int EPAD = 264;   // 256 + 8 bf16 pad (row stride ≡ 4 dwords mod 32 → 2-way, free)
constexpr int APAD = 136;   // 128 + 8 bf16 pad

using f32x4  = __attribute__((ext_vector_type(4))) float;
using bf16x8 = __attribute__((ext_vector_type(8))) short;   // 8 bf16 in 4 VGPRs

__device__ __forceinline__ short f2b(float x) {   // f32 -> bf16 RNE
  unsigned u = __builtin_bit_cast(unsigned, x);
  u += 0x7fffu + ((u >> 16) & 1u);
  return (short)(u >> 16);
}
__device__ __forceinline__ short4 f2b4(float4 v) {
  return make_short4(f2b(v.x), f2b(v.y), f2b(v.z), f2b(v.w));
}

__global__ void nef_init(float* Sbuf, unsigned int* ctrs, float* out) {
  int idx = blockIdx.x * blockDim.x + threadIdx.x;
  int stride = gridDim.x * blockDim.x;
  for (int i = idx; i < 4 * CB * DST; i += stride) Sbuf[i] = 0.f;  // 4 state buffers
  for (int i = idx; i < CB * DOUT; i += stride) out[i] = 0.f;
  if (idx < 16 * 64) ctrs[idx] = 0u;                               // barrier ctrs
}

__global__ void __launch_bounds__(256) nef_main(
    const float* __restrict__ seq,  const float* __restrict__ enc,
    const float* __restrict__ gainp,const float* __restrict__ biasp,
    const float* __restrict__ sdec, const float* __restrict__ dec,
    float* __restrict__ out, float* __restrict__ Sbuf, unsigned int* ctrs)
{
  __shared__ short E_lds[NT][EPAD];     // encoders tile  [n][k_aug]   67.6 KB
  __shared__ short SDT_lds[DST][APAD];  // state_dec^T    [d][n]       34.8 KB
  __shared__ short X_lds[BT][EPAD];     // [u_t | s_t]    [b][k_aug]   16.9 KB
  __shared__ short A_lds[BT][APAD];     // activations    [b][n]        8.7 KB
  __shared__ float gain_lds[NT];
  __shared__ float bias_lds[NT];

  const int tid  = threadIdx.x;
  const int bg   = blockIdx.x & 7;    // group's 16 blocks share an XCD (perf heuristic only)
  const int ng   = blockIdx.x >> 3;
  const int b0   = bg * BT;
  const int n0   = ng * NT;
  const int wave = tid >> 6;
  const int lane = tid & 63;
  const int l15  = lane & 15;
  const int lhi  = lane >> 4;         // 0..3
  const int kbase = lhi * 8;

  // ---- one-time: stage weights into LDS (bf16) ----
  for (int i = 0; i < 32; ++i) {                       // encoders: 128x256 f32
    int fidx = i * 256 + tid;
    int row = fidx >> 6, c4 = fidx & 63;
    const float4 v = *(const float4*)(enc + (size_t)(n0 + row) * DAUG + (c4 << 2));
    *(short4*)&E_lds[row][c4 << 2] = f2b4(v);
  }
  for (int i = 0; i < 16; ++i) {                       // state_decoders: transpose
    int fidx = i * 256 + tid;
    int n = fidx >> 5, c4 = fidx & 31;
    const float4 v = *(const float4*)(sdec + (size_t)(n0 + n) * DST + (c4 << 2));
    SDT_lds[(c4 << 2) + 0][n] = f2b(v.x);
    SDT_lds[(c4 << 2) + 1][n] = f2b(v.y);
    SDT_lds[(c4 << 2) + 2][n] = f2b(v.z);
    SDT_lds[(c4 << 2) + 3][n] = f2b(v.w);
  }
  if (tid < NT) { gain_lds[tid] = gainp[n0 + tid]; bias_lds[tid] = biasp[n0 + tid]; }

  unsigned int* ctr = ctrs + bg * 64;   // one 256B-strided ctr per group
  const int nsub0 = wave * 32, nsub1 = nsub0 + 16;

  // seq prefetch: 4 float4 per thread per step (32 rows x 32 float4-cols)
  float4 pu[4];
#pragma unroll
  for (int i = 0; i < 4; ++i) {
    int fidx = i * 256 + tid;
    int row = fidx >> 5, c4 = fidx & 31;
    pu[i] = *(const float4*)(seq + ((size_t)(b0 + row) * CT + 0) * DIN + (c4 << 2));
  }

  for (int t = 0; t < CT; ++t) {
    // ---- zero S[(t+2)&3] (agent atomic stores: write-through, LLC-visible).
    // Safe: that buffer's readers ran at step t-2 (done before any block passed
    // poll(t)); its next adders run at t+1 AFTER our step-t flag. ----
    {
      float* Sz = Sbuf + ((t + 2) & 3) * (CB * DST);
      __hip_atomic_store(&Sz[b0 * DST + ng * 256 + tid], 0.f,
                         __ATOMIC_RELAXED, __HIP_MEMORY_SCOPE_AGENT);
    }
    // ---- stage u-half (register prefetch -> LDS bf16); independent of s ----
#pragma unroll
    for (int i = 0; i < 4; ++i) {
      int fidx = i * 256 + tid;
      int row = fidx >> 5, c4 = fidx & 31;
      *(short4*)&X_lds[row][c4 << 2] = f2b4(pu[i]);
    }
    if (t + 1 < CT) {   // prefetch u_{t+1}; in flight across the poll below
#pragma unroll
      for (int i = 0; i < 4; ++i) {
        int fidx = i * 256 + tid;
        int row = fidx >> 5, c4 = fidx & 31;
        pu[i] = *(const float4*)(seq + ((size_t)(b0 + row) * CT + (t + 1)) * DIN + (c4 << 2));
      }
    }
    // ---- wait for s_t: all 16 group blocks posted step t-1 adds ----
    if (t > 0) {
      unsigned int tgt = 16u * (unsigned)t, guard = 0;
      while (__hip_atomic_load(ctr, __ATOMIC_RELAXED, __HIP_MEMORY_SCOPE_AGENT) < tgt) {
        __builtin_amdgcn_s_sleep(1);
        if (++guard > 100000u) break;   // bounded: wrong answer, never a wedge
      }
    }
    // ---- stage s-half: S f32 (LLC) -> bf16 LDS via 8B agent atomic loads ----
    {
      const float* Sr = Sbuf + (t & 3) * (CB * DST);
#pragma unroll
      for (int i = 0; i < 2; ++i) {
        int idx8 = i * 256 + tid;            // 512 chunks of 8 f32
        int row = idx8 >> 4, c8 = idx8 & 15;
        const unsigned long long* p =
            (const unsigned long long*)(Sr + (size_t)(b0 + row) * DST + c8 * 8);
        short s8[8];
#pragma unroll
        for (int q = 0; q < 4; ++q) {
          unsigned long long w = __hip_atomic_load(p + q, __ATOMIC_RELAXED,
                                                   __HIP_MEMORY_SCOPE_AGENT);
          s8[2 * q]     = f2b(__builtin_bit_cast(float, (unsigned)(w & 0xffffffffu)));
          s8[2 * q + 1] = f2b(__builtin_bit_cast(float, (unsigned)(w >> 32)));
        }
        *(short4*)&X_lds[row][DIN + c8 * 8]     = make_short4(s8[0], s8[1], s8[2], s8[3]);
        *(short4*)&X_lds[row][DIN + c8 * 8 + 4] = make_short4(s8[4], s8[5], s8[6], s8[7]);
      }
    }
    __syncthreads();   // also covers one-time weight staging at t=0

    // ---- GEMM A: (32 x 256) @ (256 x 128) -> a; wave: 2 m-tiles x 2 n-tiles ----
    f32x4 acc00 = {0,0,0,0}, acc01 = {0,0,0,0}, acc10 = {0,0,0,0}, acc11 = {0,0,0,0};
#pragma unroll
    for (int kk = 0; kk < 8; ++kk) {
      bf16x8 a0 = *(const bf16x8*)&X_lds[l15][kk * 32 + kbase];
      bf16x8 a1 = *(const bf16x8*)&X_lds[16 + l15][kk * 32 + kbase];
      bf16x8 e0 = *(const bf16x8*)&E_lds[nsub0 + l15][kk * 32 + kbase];
      bf16x8 e1 = *(const bf16x8*)&E_lds[nsub1 + l15][kk * 32 + kbase];
      acc00 = __builtin_amdgcn_mfma_f32_16x16x32_bf16(a0, e0, acc00, 0, 0, 0);
      acc01 = __builtin_amdgcn_mfma_f32_16x16x32_bf16(a0, e1, acc01, 0, 0, 0);
      acc10 = __builtin_amdgcn_mfma_f32_16x16x32_bf16(a1, e0, acc10, 0, 0, 0);
      acc11 = __builtin_amdgcn_mfma_f32_16x16x32_bf16(a1, e1, acc11, 0, 0, 0);
    }
    {   // epilogue: relu(gain*x + bias) -> bf16 a-tile in LDS
      const int nc0 = nsub0 + l15, nc1 = nsub1 + l15;
      const float g0 = gain_lds[nc0], bi0 = bias_lds[nc0];
      const float g1 = gain_lds[nc1], bi1 = bias_lds[nc1];
#pragma unroll
      for (int j = 0; j < 4; ++j) {   // C/D: col=lane&15, row=(lane>>4)*4+j
        A_lds[lhi * 4 + j][nc0]      = f2b(fmaxf(g0 * acc00[j] + bi0, 0.f));
        A_lds[lhi * 4 + j][nc1]      = f2b(fmaxf(g1 * acc01[j] + bi1, 0.f));
        A_lds[16 + lhi * 4 + j][nc0] = f2b(fmaxf(g0 * acc10[j] + bi0, 0.f));
        A_lds[16 + lhi * 4 + j][nc1] = f2b(fmaxf(g1 * acc11[j] + bi1, 0.f));
      }
    }
    __syncthreads();

    if (t != CT - 1) {
      // ---- GEMM B: (32 x 128) @ (128 x 128) -> partial s_{t+1} ----
      f32x4 p00 = {0,0,0,0}, p01 = {0,0,0,0}, p10 = {0,0,0,0}, p11 = {0,0,0,0};
      const int d0 = nsub0 + l15, d1 = nsub1 + l15;
#pragma unroll
      for (int kk = 0; kk < 4; ++kk) {
        bf16x8 a0 = *(const bf16x8*)&A_lds[l15][kk * 32 + kbase];
        bf16x8 a1 = *(const bf16x8*)&A_lds[16 + l15][kk * 32 + kbase];
        bf16x8 s0 = *(const bf16x8*)&SDT_lds[d0][kk * 32 + kbase];
        bf16x8 s1 = *(const bf16x8*)&SDT_lds[d1][kk * 32 + kbase];
        p00 = __builtin_amdgcn_mfma_f32_16x16x32_bf16(a0, s0, p00, 0, 0, 0);
        p01 = __builtin_amdgcn_mfma_f32_16x16x32_bf16(a0, s1, p01, 0, 0, 0);
        p10 = __builtin_amdgcn_mfma_f32_16x16x32_bf16(a1, s0, p10, 0, 0, 0);
        p11 = __builtin_amdgcn_mfma_f32_16x16x32_bf16(a1, s1, p11, 0, 0, 0);
      }
      // ---- memory-side f32 RMWs into S[(t+1)&3] (HW fadd, no CAS loop) ----
      float* Sw = Sbuf + ((t + 1) & 3) * (CB * DST);
#pragma unroll
      for (int j = 0; j < 4; ++j) {
        unsafeAtomicAdd(&Sw[(size_t)(b0 + lhi * 4 + j) * DST + d0],      p00[j]);
        unsafeAtomicAdd(&Sw[(size_t)(b0 + lhi * 4 + j) * DST + d1],      p01[j]);
        unsafeAtomicAdd(&Sw[(size_t)(b0 + 16 + lhi * 4 + j) * DST + d0], p10[j]);
        unsafeAtomicAdd(&Sw[(size_t)(b0 + 16 + lhi * 4 + j) * DST + d1], p11[j]);
      }
      // ---- flag: adds are drained by syncthreads' vmcnt wait; no fence needed ----
      __syncthreads();
      if (tid == 0) atomicAdd(ctr, 1u);
    } else {
      // ---- final step: out partial = a_final @ decoders[n0:n0+128] ----
      f32x4 o0 = {0,0,0,0}, o1 = {0,0,0,0};
      const int ocol = wave * 16 + l15;   // 4 waves x 16 = DOUT
#pragma unroll
      for (int kk = 0; kk < 4; ++kk) {
        bf16x8 a0 = *(const bf16x8*)&A_lds[l15][kk * 32 + kbase];
        bf16x8 a1 = *(const bf16x8*)&A_lds[16 + l15][kk * 32 + kbase];
        bf16x8 bfD;
#pragma unroll
        for (int j = 0; j < 8; ++j)
          bfD[j] = f2b(dec[(size_t)(n0 + kk * 32 + kbase + j) * DOUT + ocol]);
        o0 = __builtin_amdgcn_mfma_f32_16x16x32_bf16(a0, bfD, o0, 0, 0, 0);
        o1 = __builtin_amdgcn_mfma_f32_16x16x32_bf16(a1, bfD, o1, 0, 0, 0);
      }
#pragma unroll
      for (int j = 0; j < 4; ++j) {       // one-time 16-way K-split reduction
        unsafeAtomicAdd(&out[(size_t)(b0 + lhi * 4 + j) * DOUT + ocol], o0[j]);
        unsafeAtomicAdd(&out[(size_t)(b0 + 16 + lhi * 4 + j) * DOUT + ocol], o1[j]);
      }
    }
  }
}

extern "C" void kernel_launch(void* const* d_in, const int* in_sizes, int n_in,
                              void* d_out, int out_size, void* d_ws, size_t ws_size,
                              hipStream_t stream) {
  const float* seq   = (const float*)d_in[0];
  const float* enc   = (const float*)d_in[1];
  const float* gainp = (const float*)d_in[2];
  const float* biasp = (const float*)d_in[3];
  const float* sdec  = (const float*)d_in[4];
  const float* dec   = (const float*)d_in[5];
  float* out = (float*)d_out;

  // workspace: Sbuf f32 [4][256][128] = 512 KB | ctrs 4 KB
  float* Sbuf = (float*)d_ws;
  unsigned int* ctrs = (unsigned int*)((char*)d_ws + (size_t)4 * CB * DST * sizeof(float));

  nef_init<<<128, 256, 0, stream>>>(Sbuf, ctrs, out);
  nef_main<<<dim3(NBG * NNG), dim3(256), 0, stream>>>(seq, enc, gainp, biasp,
                                                      sdec, dec, out, Sbuf, ctrs);
}